// Round 5
// baseline (479.104 us; speedup 1.0000x reference)
//
#include <hip/hip_runtime.h>

#define NN 100000
#define NE 1600000
#define FD 128
#define NG 64
#define OUTD 64

typedef __attribute__((ext_vector_type(8))) short bf16x8;
typedef __attribute__((ext_vector_type(4))) float f32x4;
typedef __attribute__((ext_vector_type(8))) unsigned short u16x8;

static __device__ __forceinline__ void atomAddF(float* p, float v) {
    __hip_atomic_fetch_add(p, v, __ATOMIC_RELAXED, __HIP_MEMORY_SCOPE_AGENT);
}
static __device__ __forceinline__ int atomAddI(int* p, int v) {
    return __hip_atomic_fetch_add(p, v, __ATOMIC_RELAXED, __HIP_MEMORY_SCOPE_AGENT);
}
// fp32 -> bf16 round-to-nearest-even
static __device__ __forceinline__ unsigned short f2bf(float f) {
    unsigned int u = __float_as_uint(f);
    u += 0x7FFFu + ((u >> 16) & 1u);
    return (unsigned short)(u >> 16);
}
static __device__ __forceinline__ float bf2f(unsigned short h) {
    return __uint_as_float(((unsigned int)h) << 16);
}

// ========== fused degree histogram + per-graph node counts ==========
__global__ void k_histgc(const int* __restrict__ dst, const int* __restrict__ gid,
                         int* __restrict__ degi, float* __restrict__ gcount) {
    __shared__ float c[NG];
    if (threadIdx.x < NG) c[threadIdx.x] = 0.0f;
    __syncthreads();
    int i = blockIdx.x * blockDim.x + threadIdx.x;
    if (i < NE) atomAddI(&degi[dst[i]], 1);
    if (i < NN) atomicAdd(&c[gid[i]], 1.0f);
    __syncthreads();
    if (threadIdx.x < NG) {
        float v = c[threadIdx.x];
        if (v != 0.0f) atomAddF(&gcount[threadIdx.x], v);
    }
}

// ========== CSR range claim: off[v] = atomic bump by deg (order-free) ==========
// Wave-level scan + one global atomic per wave. cursor starts at off.
__global__ void k_off(const int* __restrict__ degi, int* __restrict__ cnt,
                      int* __restrict__ off, int* __restrict__ cursor) {
    int i = blockIdx.x * 256 + threadIdx.x;
    int lane = threadIdx.x & 63;
    int d = (i < NN) ? degi[i] : 0;
    int incl = d;
    #pragma unroll
    for (int s = 1; s < 64; s <<= 1) {
        int n = __shfl_up(incl, s, 64);
        if (lane >= s) incl += n;
    }
    int base = 0;
    if (lane == 63) base = atomAddI(cnt, incl);
    base = __shfl(base, 63, 64);
    if (i < NN) {
        int o = base + incl - d;
        off[i] = o;
        cursor[i] = o;
    }
}

// ========== CSR fill: eidx[pos] = src, bucketed by dst ==========
// After this, cursor[v] == off[v] + deg[v] (bucket end).
__global__ void k_fill(const int* __restrict__ src, const int* __restrict__ dst,
                       int* __restrict__ cursor, int* __restrict__ eidx) {
    int e = blockIdx.x * blockDim.x + threadIdx.x;
    if (e < NE) {
        int v = dst[e];
        int p = atomAddI(&cursor[v], 1);
        eidx[p] = src[e];
    }
}

// ========== W transpose + bf16 convert (Wt[n][k]) ==========
__global__ void k_wt(const float* __restrict__ W1, const float* __restrict__ W2,
                     unsigned short* __restrict__ W1t, unsigned short* __restrict__ W2t) {
    int idx = blockIdx.x * 256 + threadIdx.x;      // 0..32767
    const float* W = (idx < 16384) ? W1 : W2;
    unsigned short* Wt = (idx < 16384) ? W1t : W2t;
    int i = idx & 16383;
    int k = i >> 7, n = i & 127;
    Wt[n * 128 + k] = f2bf(W[i]);
}

// ========== MFMA GEMM: Y = A @ W (bf16 LDS, fp32 acc, bf16 out) ==========
// 64 nodes x 128 feats per block, 4 waves; T2 XOR swizzle on LDS rows.
template <bool A_FP32>
__global__ __launch_bounds__(256) void k_gemm(
    const void* __restrict__ Ain, const unsigned short* __restrict__ Wt,
    unsigned short* __restrict__ Y)
{
    __shared__ unsigned short As[64 * 128];    // 16 KB
    __shared__ unsigned short Bs[128 * 128];   // 32 KB
    const int tid = threadIdx.x;
    const int base = blockIdx.x * 64;
    char* AsB = reinterpret_cast<char*>(As);
    char* BsB = reinterpret_cast<char*>(Bs);

    {
        const u16x8* Wv = reinterpret_cast<const u16x8*>(Wt);
        #pragma unroll
        for (int i = 0; i < 8; ++i) {
            int idx = i * 256 + tid;
            int n = idx >> 4, s = idx & 15;
            int soff = (s * 16) ^ ((n & 7) << 4);
            *reinterpret_cast<u16x8*>(BsB + n * 256 + soff) = Wv[idx];
        }
    }
    if (A_FP32) {
        const float4* Av = reinterpret_cast<const float4*>(Ain);
        #pragma unroll
        for (int i = 0; i < 8; ++i) {
            int idx = i * 256 + tid;
            int r = idx >> 5, c4 = idx & 31;
            int row = base + r;
            float4 v;
            if (row < NN) v = Av[(size_t)row * 32 + c4];
            else { v.x = v.y = v.z = v.w = 0.0f; }
            unsigned short h[4] = { f2bf(v.x), f2bf(v.y), f2bf(v.z), f2bf(v.w) };
            int soff = (c4 * 8) ^ ((r & 7) << 4);
            *reinterpret_cast<uint2*>(AsB + r * 256 + soff) = *reinterpret_cast<uint2*>(h);
        }
    } else {
        const u16x8* Av = reinterpret_cast<const u16x8*>(Ain);
        #pragma unroll
        for (int i = 0; i < 4; ++i) {
            int idx = i * 256 + tid;
            int r = idx >> 4, s = idx & 15;
            int row = base + r;
            u16x8 v;
            if (row < NN) v = Av[(size_t)row * 16 + s];
            else v = (u16x8){0,0,0,0,0,0,0,0};
            int soff = (s * 16) ^ ((r & 7) << 4);
            *reinterpret_cast<u16x8*>(AsB + r * 256 + soff) = v;
        }
    }
    __syncthreads();

    const int lane = tid & 63;
    const int w = tid >> 6;
    const int rowb = w * 16;
    const int r = rowb + (lane & 15);
    const int kb = lane >> 4;
    const int n = lane & 15;

    bf16x8 a[4];
    #pragma unroll
    for (int kt = 0; kt < 4; ++kt) {
        int boff = (kt * 64 + kb * 16) ^ ((r & 7) << 4);
        a[kt] = *reinterpret_cast<bf16x8*>(AsB + r * 256 + boff);
    }

    f32x4 acc[8];
    #pragma unroll
    for (int ct = 0; ct < 8; ++ct) acc[ct] = (f32x4){0.f, 0.f, 0.f, 0.f};

    #pragma unroll
    for (int ct = 0; ct < 8; ++ct) {
        int col = ct * 16 + n;
        #pragma unroll
        for (int kt = 0; kt < 4; ++kt) {
            int boff = (kt * 64 + kb * 16) ^ ((col & 7) << 4);
            bf16x8 b = *reinterpret_cast<bf16x8*>(BsB + col * 256 + boff);
            acc[ct] = __builtin_amdgcn_mfma_f32_16x16x32_bf16(a[kt], b, acc[ct], 0, 0, 0);
        }
    }

    const int rbase = base + rowb + (lane >> 4) * 4;
    #pragma unroll
    for (int reg = 0; reg < 4; ++reg) {
        int node = rbase + reg;
        if (node < NN) {
            #pragma unroll
            for (int ct = 0; ct < 8; ++ct)
                Y[(size_t)node * FD + ct * 16 + n] = f2bf(acc[ct][reg]);
        }
    }
}

// ===== gather: H[v] = relu(Y[v] + mean_{u->v} Y[u] + bias); 16 thr/node =====
// 4-edge unroll -> 4 independent 16B row loads in flight per thread.
// POOL: per-graph sums via LDS (gid sorted), block covers 16 nodes.
template <bool POOL>
__global__ __launch_bounds__(256) void k_agg(
    const unsigned short* __restrict__ Y, const int* __restrict__ off,
    const int* __restrict__ end, const int* __restrict__ eidx,
    const float* __restrict__ bias, unsigned short* __restrict__ H,
    const int* __restrict__ gid, float* __restrict__ hg_sum)
{
    __shared__ float hl[FD];
    int gid0 = 0;
    if (POOL) {
        if (threadIdx.x < FD) hl[threadIdx.x] = 0.0f;
        gid0 = gid[blockIdx.x * 16];
        __syncthreads();
    }
    const int t = blockIdx.x * 256 + threadIdx.x;
    const int v = t >> 4;          // node
    const int l = t & 15;          // 8-feature slice
    const int e0 = off[v], e1 = end[v];

    float a[8];
    #pragma unroll
    for (int j = 0; j < 8; ++j) a[j] = 0.0f;

    const u16x8* Yv = reinterpret_cast<const u16x8*>(Y);
    int e = e0;
    for (; e + 4 <= e1; e += 4) {
        int s0 = eidx[e + 0], s1 = eidx[e + 1];
        int s2 = eidx[e + 2], s3 = eidx[e + 3];
        u16x8 p0 = Yv[(size_t)s0 * 16 + l];
        u16x8 p1 = Yv[(size_t)s1 * 16 + l];
        u16x8 p2 = Yv[(size_t)s2 * 16 + l];
        u16x8 p3 = Yv[(size_t)s3 * 16 + l];
        #pragma unroll
        for (int j = 0; j < 8; ++j)
            a[j] += (bf2f(p0[j]) + bf2f(p1[j])) + (bf2f(p2[j]) + bf2f(p3[j]));
    }
    for (; e < e1; ++e) {
        u16x8 p = Yv[(size_t)eidx[e] * 16 + l];
        #pragma unroll
        for (int j = 0; j < 8; ++j) a[j] += bf2f(p[j]);
    }

    const float inv = 1.0f / fmaxf((float)(e1 - e0), 1.0f);
    u16x8 sv = Yv[(size_t)v * 16 + l];
    const float4* bp = reinterpret_cast<const float4*>(bias + l * 8);
    float4 b0 = bp[0], b1 = bp[1];
    const float* bb[8] = { &b0.x, &b0.y, &b0.z, &b0.w, &b1.x, &b1.y, &b1.z, &b1.w };

    float hv[8];
    #pragma unroll
    for (int j = 0; j < 8; ++j)
        hv[j] = fmaxf(bf2f(sv[j]) + a[j] * inv + *bb[j], 0.0f);

    if (!POOL) {
        u16x8 o;
        #pragma unroll
        for (int j = 0; j < 8; ++j) o[j] = f2bf(hv[j]);
        reinterpret_cast<u16x8*>(H)[(size_t)v * 16 + l] = o;
    } else {
        int g = gid[v];
        int fo = l * 8;
        if (g == gid0) {
            #pragma unroll
            for (int j = 0; j < 8; ++j) atomicAdd(&hl[fo + j], hv[j]);
        } else {
            #pragma unroll
            for (int j = 0; j < 8; ++j) atomAddF(&hg_sum[(size_t)g * FD + fo + j], hv[j]);
        }
        __syncthreads();
        if (threadIdx.x < FD)
            atomAddF(&hg_sum[(size_t)gid0 * FD + threadIdx.x], hl[threadIdx.x]);
    }
}

// ===== fused decoder: one block per graph =====
// hg = hg_sum/cnt -> out[0:8192]; t1 = relu(hg@Wd1+bd1); rec = t1@Wd2+bd2 -> out[8192:]
__global__ __launch_bounds__(128) void k_dec(
    const float* __restrict__ hg_sum, const float* __restrict__ gcount,
    const float* __restrict__ Wd1, const float* __restrict__ bd1,
    const float* __restrict__ Wd2, const float* __restrict__ bd2,
    float* __restrict__ out)
{
    __shared__ float hgL[FD];
    __shared__ float t1L[FD];
    const int g = blockIdx.x;
    const int t = threadIdx.x;
    const float invc = 1.0f / fmaxf(gcount[g], 1.0f);

    float v = hg_sum[(size_t)g * FD + t] * invc;
    hgL[t] = v;
    out[(size_t)g * FD + t] = v;
    __syncthreads();

    float acc = bd1[t];
    #pragma unroll 8
    for (int k = 0; k < FD; ++k)
        acc += hgL[k] * Wd1[k * FD + t];
    t1L[t] = fmaxf(acc, 0.0f);
    __syncthreads();

    if (t < OUTD) {
        float acc2 = bd2[t];
        #pragma unroll 8
        for (int k = 0; k < FD; ++k)
            acc2 += t1L[k] * Wd2[k * OUTD + t];
        out[NG * FD + (size_t)g * OUTD + t] = acc2;
    }
}

extern "C" void kernel_launch(void* const* d_in, const int* in_sizes, int n_in,
                              void* d_out, int out_size, void* d_ws, size_t ws_size,
                              hipStream_t stream) {
    const float* feat = (const float*)d_in[0];
    const int*   src  = (const int*)d_in[1];
    const int*   dst  = (const int*)d_in[2];
    const int*   gid  = (const int*)d_in[3];
    const float* W1   = (const float*)d_in[4];
    const float* b1   = (const float*)d_in[5];
    const float* W2   = (const float*)d_in[6];
    const float* b2   = (const float*)d_in[7];
    const float* Wd1  = (const float*)d_in[8];
    const float* bd1  = (const float*)d_in[9];
    const float* Wd2  = (const float*)d_in[10];
    const float* bd2  = (const float*)d_in[11];
    float* out = (float*)d_out;

    // workspace layout (element offsets; 16B-aligned where vector-accessed)
    char* wsb = (char*)d_ws;
    int*   degi   = (int*)wsb;                              // [100000]
    float* gcount = (float*)(wsb + 100000ll * 4);           // [64]
    float* hg_sum = (float*)(wsb + 100064ll * 4);           // [8192]
    int*   cnt    = (int*)(wsb + 108256ll * 4);             // [1] (+pad to 108260)
    int*   off    = (int*)(wsb + 108260ll * 4);             // [100000]
    int*   cursor = (int*)(wsb + 208260ll * 4);             // [100000]
    int*   eidx   = (int*)(wsb + 308260ll * 4);             // [1600000]
    unsigned short* W1t = (unsigned short*)(wsb + 1908260ll * 4);  // bf16 [16384]
    unsigned short* W2t = (unsigned short*)(wsb + 1916452ll * 4);  // bf16 [16384]
    unsigned short* Yb  = (unsigned short*)(wsb + 1924644ll * 4);  // bf16 [12800000]
    unsigned short* H1  = (unsigned short*)(wsb + 8324644ll * 4);  // bf16 [12800000]

    // zero degi + gcount + hg_sum + cnt
    hipMemsetAsync(d_ws, 0, (size_t)108260 * 4, stream);

    // CSR build (order-free buckets) + weight prep
    k_histgc<<<(NE + 255) / 256, 256, 0, stream>>>(dst, gid, degi, gcount);
    k_off   <<<(NN + 255) / 256, 256, 0, stream>>>(degi, cnt, off, cursor);
    k_fill  <<<(NE + 255) / 256, 256, 0, stream>>>(src, dst, cursor, eidx);
    k_wt    <<<128, 256, 0, stream>>>(W1, W2, W1t, W2t);

    // layer 1: y1 = x @ W1 (MFMA), h1 = relu(y1 + agg(y1) + b1)
    k_gemm<true><<<(NN + 63) / 64, 256, 0, stream>>>(feat, W1t, Yb);
    k_agg<false><<<NN * 16 / 256, 256, 0, stream>>>(Yb, off, cursor, eidx, b1, H1, nullptr, nullptr);

    // layer 2: y2 = h1 @ W2 (MFMA), h2 = relu(y2 + agg(y2) + b2) fused into pool
    k_gemm<false><<<(NN + 63) / 64, 256, 0, stream>>>(H1, W2t, Yb);
    k_agg<true><<<NN * 16 / 256, 256, 0, stream>>>(Yb, off, cursor, eidx, b2, nullptr, gid, hg_sum);

    // fused pool-divide + decoder
    k_dec<<<NG, 128, 0, stream>>>(hg_sum, gcount, Wd1, bd1, Wd2, bd2, out);
}

// Round 6
// 474.215 us; speedup vs baseline: 1.0103x; 1.0103x over previous
//
#include <hip/hip_runtime.h>

#define NN 100000
#define NE 1600000
#define FD 128
#define NG 64
#define OUTD 64

typedef __attribute__((ext_vector_type(8))) short bf16x8;
typedef __attribute__((ext_vector_type(4))) float f32x4;
typedef __attribute__((ext_vector_type(8))) unsigned short u16x8;

static __device__ __forceinline__ void atomAddF(float* p, float v) {
    __hip_atomic_fetch_add(p, v, __ATOMIC_RELAXED, __HIP_MEMORY_SCOPE_AGENT);
}
static __device__ __forceinline__ int atomAddI(int* p, int v) {
    return __hip_atomic_fetch_add(p, v, __ATOMIC_RELAXED, __HIP_MEMORY_SCOPE_AGENT);
}
// fp32 -> bf16 round-to-nearest-even
static __device__ __forceinline__ unsigned short f2bf(float f) {
    unsigned int u = __float_as_uint(f);
    u += 0x7FFFu + ((u >> 16) & 1u);
    return (unsigned short)(u >> 16);
}
static __device__ __forceinline__ float bf2f(unsigned short h) {
    return __uint_as_float(((unsigned int)h) << 16);
}

// ========== fused degree histogram + per-graph node counts ==========
__global__ void k_histgc(const int* __restrict__ dst, const int* __restrict__ gid,
                         int* __restrict__ degi, float* __restrict__ gcount) {
    __shared__ float c[NG];
    if (threadIdx.x < NG) c[threadIdx.x] = 0.0f;
    __syncthreads();
    int i = blockIdx.x * blockDim.x + threadIdx.x;
    if (i < NE) atomAddI(&degi[dst[i]], 1);
    if (i < NN) atomicAdd(&c[gid[i]], 1.0f);
    __syncthreads();
    if (threadIdx.x < NG) {
        float v = c[threadIdx.x];
        if (v != 0.0f) atomAddF(&gcount[threadIdx.x], v);
    }
}

// ========== CSR range claim, buckets padded to multiples of 16 ==========
// off[v] = start; cursor[v] = start (fill bumps it); padding slots pre-filled
// with dummy index NN (Y row NN is zeroed -> contributes 0 to sums).
__global__ void k_off(const int* __restrict__ degi, int* __restrict__ cnt,
                      int* __restrict__ off, int* __restrict__ cursor,
                      int* __restrict__ eidx) {
    int i = blockIdx.x * 256 + threadIdx.x;
    int lane = threadIdx.x & 63;
    int d = (i < NN) ? degi[i] : 0;
    int rd = (d + 15) & ~15;
    int incl = rd;
    #pragma unroll
    for (int s = 1; s < 64; s <<= 1) {
        int n = __shfl_up(incl, s, 64);
        if (lane >= s) incl += n;
    }
    int base = 0;
    if (lane == 63) base = atomAddI(cnt, incl);
    base = __shfl(base, 63, 64);
    if (i < NN) {
        int o = base + incl - rd;
        off[i] = o;
        cursor[i] = o;
        for (int j = d; j < rd; ++j) eidx[o + j] = NN;
    }
}

// ========== CSR fill: eidx[pos] = src, bucketed by dst ==========
__global__ void k_fill(const int* __restrict__ src, const int* __restrict__ dst,
                       int* __restrict__ cursor, int* __restrict__ eidx) {
    int e = blockIdx.x * blockDim.x + threadIdx.x;
    if (e < NE) {
        int v = dst[e];
        int p = atomAddI(&cursor[v], 1);
        eidx[p] = src[e];
    }
}

// ========== W transpose + bf16 convert (Wt[n][k]) ==========
__global__ void k_wt(const float* __restrict__ W1, const float* __restrict__ W2,
                     unsigned short* __restrict__ W1t, unsigned short* __restrict__ W2t) {
    int idx = blockIdx.x * 256 + threadIdx.x;      // 0..32767
    const float* W = (idx < 16384) ? W1 : W2;
    unsigned short* Wt = (idx < 16384) ? W1t : W2t;
    int i = idx & 16383;
    int k = i >> 7, n = i & 127;
    Wt[n * 128 + k] = f2bf(W[i]);
}

// ========== MFMA GEMM: Y = A @ W (bf16 LDS, fp32 acc, bf16 out) ==========
// 64 nodes x 128 feats per block, 4 waves; T2 XOR swizzle on LDS rows.
template <bool A_FP32>
__global__ __launch_bounds__(256) void k_gemm(
    const void* __restrict__ Ain, const unsigned short* __restrict__ Wt,
    unsigned short* __restrict__ Y)
{
    __shared__ unsigned short As[64 * 128];    // 16 KB
    __shared__ unsigned short Bs[128 * 128];   // 32 KB
    const int tid = threadIdx.x;
    const int base = blockIdx.x * 64;
    char* AsB = reinterpret_cast<char*>(As);
    char* BsB = reinterpret_cast<char*>(Bs);

    {
        const u16x8* Wv = reinterpret_cast<const u16x8*>(Wt);
        #pragma unroll
        for (int i = 0; i < 8; ++i) {
            int idx = i * 256 + tid;
            int n = idx >> 4, s = idx & 15;
            int soff = (s * 16) ^ ((n & 7) << 4);
            *reinterpret_cast<u16x8*>(BsB + n * 256 + soff) = Wv[idx];
        }
    }
    if (A_FP32) {
        const float4* Av = reinterpret_cast<const float4*>(Ain);
        #pragma unroll
        for (int i = 0; i < 8; ++i) {
            int idx = i * 256 + tid;
            int r = idx >> 5, c4 = idx & 31;
            int row = base + r;
            float4 v;
            if (row < NN) v = Av[(size_t)row * 32 + c4];
            else { v.x = v.y = v.z = v.w = 0.0f; }
            unsigned short h[4] = { f2bf(v.x), f2bf(v.y), f2bf(v.z), f2bf(v.w) };
            int soff = (c4 * 8) ^ ((r & 7) << 4);
            *reinterpret_cast<uint2*>(AsB + r * 256 + soff) = *reinterpret_cast<uint2*>(h);
        }
    } else {
        const u16x8* Av = reinterpret_cast<const u16x8*>(Ain);
        #pragma unroll
        for (int i = 0; i < 4; ++i) {
            int idx = i * 256 + tid;
            int r = idx >> 4, s = idx & 15;
            int row = base + r;
            u16x8 v;
            if (row < NN) v = Av[(size_t)row * 16 + s];
            else v = (u16x8){0,0,0,0,0,0,0,0};
            int soff = (s * 16) ^ ((r & 7) << 4);
            *reinterpret_cast<u16x8*>(AsB + r * 256 + soff) = v;
        }
    }
    __syncthreads();

    const int lane = tid & 63;
    const int w = tid >> 6;
    const int rowb = w * 16;
    const int r = rowb + (lane & 15);
    const int kb = lane >> 4;
    const int n = lane & 15;

    bf16x8 a[4];
    #pragma unroll
    for (int kt = 0; kt < 4; ++kt) {
        int boff = (kt * 64 + kb * 16) ^ ((r & 7) << 4);
        a[kt] = *reinterpret_cast<bf16x8*>(AsB + r * 256 + boff);
    }

    f32x4 acc[8];
    #pragma unroll
    for (int ct = 0; ct < 8; ++ct) acc[ct] = (f32x4){0.f, 0.f, 0.f, 0.f};

    #pragma unroll
    for (int ct = 0; ct < 8; ++ct) {
        int col = ct * 16 + n;
        #pragma unroll
        for (int kt = 0; kt < 4; ++kt) {
            int boff = (kt * 64 + kb * 16) ^ ((col & 7) << 4);
            bf16x8 b = *reinterpret_cast<bf16x8*>(BsB + col * 256 + boff);
            acc[ct] = __builtin_amdgcn_mfma_f32_16x16x32_bf16(a[kt], b, acc[ct], 0, 0, 0);
        }
    }

    const int rbase = base + rowb + (lane >> 4) * 4;
    #pragma unroll
    for (int reg = 0; reg < 4; ++reg) {
        int node = rbase + reg;
        if (node < NN) {
            #pragma unroll
            for (int ct = 0; ct < 8; ++ct)
                Y[(size_t)node * FD + ct * 16 + n] = f2bf(acc[ct][reg]);
        }
    }
}

// ===== gather: H[v] = relu(Y[v] + mean_{u->v} Y[u] + bias); 16 thr/node =====
// Buckets are padded to 16k edges (dummy idx NN -> zero row), so the edge loop
// is a fully-unrolled 16-chunk: 1 coalesced eidx load + 16 shfl-broadcast
// independent row loads in flight. POOL: per-graph sums via LDS (gid sorted).
template <bool POOL>
__global__ __launch_bounds__(256) void k_agg(
    const unsigned short* __restrict__ Y, const int* __restrict__ off,
    const int* __restrict__ degi, const int* __restrict__ eidx,
    const float* __restrict__ bias, unsigned short* __restrict__ H,
    const int* __restrict__ gid, float* __restrict__ hg_sum)
{
    __shared__ float hl[FD];
    int gid0 = 0;
    if (POOL) {
        if (threadIdx.x < FD) hl[threadIdx.x] = 0.0f;
        gid0 = gid[blockIdx.x * 16];
        __syncthreads();
    }
    const int t = blockIdx.x * 256 + threadIdx.x;
    const int v = t >> 4;                 // node
    const int l = t & 15;                 // 8-feature slice
    const int gb = threadIdx.x & 48;      // 16-lane group base within wave
    const int e0 = off[v];
    const int d  = degi[v];
    const int pd = (d + 15) & ~15;        // padded bucket size

    float a[8];
    #pragma unroll
    for (int j = 0; j < 8; ++j) a[j] = 0.0f;

    const u16x8* Yv = reinterpret_cast<const u16x8*>(Y);
    const int eend = e0 + pd;
    for (int e = e0; e < eend; e += 16) {
        int myidx = eidx[e + l];          // 16 edge indices per group, coalesced
        #pragma unroll
        for (int j = 0; j < 16; ++j) {
            int s = __shfl(myidx, gb + j, 64);
            u16x8 p = Yv[(size_t)s * 16 + l];
            #pragma unroll
            for (int jj = 0; jj < 8; ++jj) a[jj] += bf2f(p[jj]);
        }
    }

    const float inv = 1.0f / fmaxf((float)d, 1.0f);
    u16x8 sv = Yv[(size_t)v * 16 + l];
    const float4* bp = reinterpret_cast<const float4*>(bias + l * 8);
    float4 b0 = bp[0], b1 = bp[1];
    const float* bb[8] = { &b0.x, &b0.y, &b0.z, &b0.w, &b1.x, &b1.y, &b1.z, &b1.w };

    float hv[8];
    #pragma unroll
    for (int j = 0; j < 8; ++j)
        hv[j] = fmaxf(bf2f(sv[j]) + a[j] * inv + *bb[j], 0.0f);

    if (!POOL) {
        u16x8 o;
        #pragma unroll
        for (int j = 0; j < 8; ++j) o[j] = f2bf(hv[j]);
        reinterpret_cast<u16x8*>(H)[(size_t)v * 16 + l] = o;
    } else {
        int g = gid[v];
        int fo = l * 8;
        if (g == gid0) {
            #pragma unroll
            for (int j = 0; j < 8; ++j) atomicAdd(&hl[fo + j], hv[j]);
        } else {
            #pragma unroll
            for (int j = 0; j < 8; ++j) atomAddF(&hg_sum[(size_t)g * FD + fo + j], hv[j]);
        }
        __syncthreads();
        if (threadIdx.x < FD)
            atomAddF(&hg_sum[(size_t)gid0 * FD + threadIdx.x], hl[threadIdx.x]);
    }
}

// ===== fused decoder: one block per graph =====
__global__ __launch_bounds__(128) void k_dec(
    const float* __restrict__ hg_sum, const float* __restrict__ gcount,
    const float* __restrict__ Wd1, const float* __restrict__ bd1,
    const float* __restrict__ Wd2, const float* __restrict__ bd2,
    float* __restrict__ out)
{
    __shared__ float hgL[FD];
    __shared__ float t1L[FD];
    const int g = blockIdx.x;
    const int t = threadIdx.x;
    const float invc = 1.0f / fmaxf(gcount[g], 1.0f);

    float v = hg_sum[(size_t)g * FD + t] * invc;
    hgL[t] = v;
    out[(size_t)g * FD + t] = v;
    __syncthreads();

    float acc = bd1[t];
    #pragma unroll 8
    for (int k = 0; k < FD; ++k)
        acc += hgL[k] * Wd1[k * FD + t];
    t1L[t] = fmaxf(acc, 0.0f);
    __syncthreads();

    if (t < OUTD) {
        float acc2 = bd2[t];
        #pragma unroll 8
        for (int k = 0; k < FD; ++k)
            acc2 += t1L[k] * Wd2[k * OUTD + t];
        out[NG * FD + (size_t)g * OUTD + t] = acc2;
    }
}

extern "C" void kernel_launch(void* const* d_in, const int* in_sizes, int n_in,
                              void* d_out, int out_size, void* d_ws, size_t ws_size,
                              hipStream_t stream) {
    const float* feat = (const float*)d_in[0];
    const int*   src  = (const int*)d_in[1];
    const int*   dst  = (const int*)d_in[2];
    const int*   gid  = (const int*)d_in[3];
    const float* W1   = (const float*)d_in[4];
    const float* b1   = (const float*)d_in[5];
    const float* W2   = (const float*)d_in[6];
    const float* b2   = (const float*)d_in[7];
    const float* Wd1  = (const float*)d_in[8];
    const float* bd1  = (const float*)d_in[9];
    const float* Wd2  = (const float*)d_in[10];
    const float* bd2  = (const float*)d_in[11];
    float* out = (float*)d_out;

    // workspace layout (4-byte-word offsets; 16B-aligned where vector-accessed)
    char* wsb = (char*)d_ws;
    int*   degi   = (int*)wsb;                              // [100000]
    float* gcount = (float*)(wsb + 100000ll * 4);           // [64]
    float* hg_sum = (float*)(wsb + 100064ll * 4);           // [8192]
    int*   cnt    = (int*)(wsb + 108256ll * 4);             // [1] (pad to 108260)
    int*   off    = (int*)(wsb + 108260ll * 4);             // [100000]
    int*   cursor = (int*)(wsb + 208260ll * 4);             // [100000]
    int*   eidx   = (int*)(wsb + 308260ll * 4);             // [3200000] padded CSR
    unsigned short* W1t = (unsigned short*)(wsb + 3508260ll * 4);  // bf16 [16384]
    unsigned short* W2t = (unsigned short*)(wsb + 3516452ll * 4);  // bf16 [16384]
    unsigned short* Yb  = (unsigned short*)(wsb + 3524644ll * 4);  // bf16 [(NN+1)*128]
    unsigned short* H1  = (unsigned short*)(wsb + 9924708ll * 4);  // bf16 [NN*128]

    // zero degi + gcount + hg_sum + cnt, and the dummy Y row NN
    hipMemsetAsync(d_ws, 0, (size_t)108260 * 4, stream);
    hipMemsetAsync(Yb + (size_t)NN * FD, 0, FD * sizeof(unsigned short), stream);

    // CSR build (order-free padded buckets) + weight prep
    k_histgc<<<(NE + 255) / 256, 256, 0, stream>>>(dst, gid, degi, gcount);
    k_off   <<<(NN + 255) / 256, 256, 0, stream>>>(degi, cnt, off, cursor, eidx);
    k_fill  <<<(NE + 255) / 256, 256, 0, stream>>>(src, dst, cursor, eidx);
    k_wt    <<<128, 256, 0, stream>>>(W1, W2, W1t, W2t);

    // layer 1: y1 = x @ W1 (MFMA), h1 = relu(y1 + agg(y1) + b1)
    k_gemm<true><<<(NN + 63) / 64, 256, 0, stream>>>(feat, W1t, Yb);
    k_agg<false><<<NN * 16 / 256, 256, 0, stream>>>(Yb, off, degi, eidx, b1, H1, nullptr, nullptr);

    // layer 2: y2 = h1 @ W2 (MFMA), h2 = relu(y2 + agg(y2) + b2) fused into pool
    k_gemm<false><<<(NN + 63) / 64, 256, 0, stream>>>(H1, W2t, Yb);
    k_agg<true><<<NN * 16 / 256, 256, 0, stream>>>(Yb, off, degi, eidx, b2, nullptr, gid, hg_sum);

    // fused pool-divide + decoder
    k_dec<<<NG, 128, 0, stream>>>(hg_sum, gcount, Wd1, bd1, Wd2, bd2, out);
}

// Round 7
// 408.817 us; speedup vs baseline: 1.1719x; 1.1600x over previous
//
#include <hip/hip_runtime.h>

#define NN 100000
#define NE 1600000
#define FD 128
#define NG 64
#define OUTD 64

typedef __attribute__((ext_vector_type(8))) short bf16x8;
typedef __attribute__((ext_vector_type(4))) float f32x4;
typedef __attribute__((ext_vector_type(8))) unsigned short u16x8;

static __device__ __forceinline__ void atomAddF(float* p, float v) {
    __hip_atomic_fetch_add(p, v, __ATOMIC_RELAXED, __HIP_MEMORY_SCOPE_AGENT);
}
static __device__ __forceinline__ int atomAddI(int* p, int v) {
    return __hip_atomic_fetch_add(p, v, __ATOMIC_RELAXED, __HIP_MEMORY_SCOPE_AGENT);
}
// fp32 -> bf16 round-to-nearest-even
static __device__ __forceinline__ unsigned short f2bf(float f) {
    unsigned int u = __float_as_uint(f);
    u += 0x7FFFu + ((u >> 16) & 1u);
    return (unsigned short)(u >> 16);
}
static __device__ __forceinline__ float bf2f(unsigned short h) {
    return __uint_as_float(((unsigned int)h) << 16);
}

// ===== k_prep: [blocks 0..6249] degree hist + graph counts; [6250..] Wt + dummy row =====
__global__ __launch_bounds__(256) void k_prep(
    const int* __restrict__ dst, const int* __restrict__ gid,
    int* __restrict__ degi, float* __restrict__ gcount,
    const float* __restrict__ W1, const float* __restrict__ W2,
    unsigned short* __restrict__ W1t, unsigned short* __restrict__ W2t,
    unsigned short* __restrict__ Ydummy)
{
    if (blockIdx.x < 6250) {
        __shared__ float c[NG];
        if (threadIdx.x < NG) c[threadIdx.x] = 0.0f;
        __syncthreads();
        int i = blockIdx.x * 256 + threadIdx.x;
        if (i < NE) atomAddI(&degi[dst[i]], 1);
        if (i < NN) atomicAdd(&c[gid[i]], 1.0f);
        __syncthreads();
        if (threadIdx.x < NG) {
            float v = c[threadIdx.x];
            if (v != 0.0f) atomAddF(&gcount[threadIdx.x], v);
        }
    } else {
        int idx = (blockIdx.x - 6250) * 256 + threadIdx.x;   // 0..33023
        if (idx < 32768) {
            const float* W = (idx < 16384) ? W1 : W2;
            unsigned short* Wt = (idx < 16384) ? W1t : W2t;
            int i = idx & 16383;
            int k = i >> 7, n = i & 127;
            Wt[n * 128 + k] = f2bf(W[i]);
        } else if (idx < 32768 + FD) {
            Ydummy[idx - 32768] = 0;   // zero Y row NN (gather padding target)
        }
    }
}

// ===== CSR range claim, buckets padded to multiples of 16 =====
__global__ void k_off(const int* __restrict__ degi, int* __restrict__ cnt,
                      int* __restrict__ off, int* __restrict__ cursor,
                      int* __restrict__ eidx) {
    int i = blockIdx.x * 256 + threadIdx.x;
    int lane = threadIdx.x & 63;
    int d = (i < NN) ? degi[i] : 0;
    int rd = (d + 15) & ~15;
    int incl = rd;
    #pragma unroll
    for (int s = 1; s < 64; s <<= 1) {
        int n = __shfl_up(incl, s, 64);
        if (lane >= s) incl += n;
    }
    int base = 0;
    if (lane == 63) base = atomAddI(cnt, incl);
    base = __shfl(base, 63, 64);
    if (i < NN) {
        int o = base + incl - rd;
        off[i] = o;
        cursor[i] = o;
        for (int j = d; j < rd; ++j) eidx[o + j] = NN;
    }
}

// ===== no-LDS MFMA gemm body: Y[base..base+63] = A @ W (A fp32, frags from global) =====
static __device__ __forceinline__ void gemm_body(
    int base, const float* __restrict__ feat, const unsigned short* __restrict__ Wt,
    unsigned short* __restrict__ Y)
{
    const int lane = threadIdx.x & 63;
    const int w = threadIdx.x >> 6;
    const int r = lane & 15;
    const int kb = lane >> 4;             // 0..3
    const int row = base + w * 16 + r;
    const bool rok = row < NN;

    bf16x8 a[4];
    #pragma unroll
    for (int kt = 0; kt < 4; ++kt) {
        float4 lo = {0,0,0,0}, hi = {0,0,0,0};
        if (rok) {
            const float4* p = reinterpret_cast<const float4*>(
                feat + (size_t)row * FD + kt * 32 + kb * 8);
            lo = p[0]; hi = p[1];
        }
        bf16x8 t;
        t[0] = (short)f2bf(lo.x); t[1] = (short)f2bf(lo.y);
        t[2] = (short)f2bf(lo.z); t[3] = (short)f2bf(lo.w);
        t[4] = (short)f2bf(hi.x); t[5] = (short)f2bf(hi.y);
        t[6] = (short)f2bf(hi.z); t[7] = (short)f2bf(hi.w);
        a[kt] = t;
    }

    f32x4 acc[8];
    #pragma unroll
    for (int ct = 0; ct < 8; ++ct) acc[ct] = (f32x4){0.f, 0.f, 0.f, 0.f};

    const int n = lane & 15;
    #pragma unroll
    for (int ct = 0; ct < 8; ++ct) {
        int col = ct * 16 + n;
        #pragma unroll
        for (int kt = 0; kt < 4; ++kt) {
            bf16x8 b = *reinterpret_cast<const bf16x8*>(
                Wt + (size_t)col * FD + kt * 32 + kb * 8);
            acc[ct] = __builtin_amdgcn_mfma_f32_16x16x32_bf16(a[kt], b, acc[ct], 0, 0, 0);
        }
    }

    const int rbase = base + w * 16 + (lane >> 4) * 4;
    #pragma unroll
    for (int reg = 0; reg < 4; ++reg) {
        int node = rbase + reg;
        if (node < NN) {
            #pragma unroll
            for (int ct = 0; ct < 8; ++ct)
                Y[(size_t)node * FD + ct * 16 + n] = f2bf(acc[ct][reg]);
        }
    }
}

// ===== k_work: [g%5==0] gemm1 (no LDS); else CSR fill =====
// fill blocks keep full occupancy (no LDS anywhere in this kernel); the
// latency-bound fill hides the compute-bound gemm.
__global__ __launch_bounds__(256) void k_work(
    const int* __restrict__ src, const int* __restrict__ dst,
    int* __restrict__ cursor, int* __restrict__ eidx,
    const float* __restrict__ feat, const unsigned short* __restrict__ Wt,
    unsigned short* __restrict__ Y)
{
    int g = blockIdx.x;
    if (g % 5 == 0) {
        gemm_body((g / 5) * 64, feat, Wt, Y);
    } else {
        int fb = g - g / 5 - 1;
        int e = fb * 256 + threadIdx.x;
        if (e < NE) {
            int v = dst[e];
            int p = atomAddI(&cursor[v], 1);
            eidx[p] = src[e];
        }
    }
}

// ===== LDS MFMA GEMM for layer 2 (A bf16): Y = A @ W =====
__global__ __launch_bounds__(256) void k_gemm2(
    const unsigned short* __restrict__ Ain, const unsigned short* __restrict__ Wt,
    unsigned short* __restrict__ Y)
{
    __shared__ unsigned short As[64 * 128];    // 16 KB
    __shared__ unsigned short Bs[128 * 128];   // 32 KB
    const int tid = threadIdx.x;
    const int base = blockIdx.x * 64;
    char* AsB = reinterpret_cast<char*>(As);
    char* BsB = reinterpret_cast<char*>(Bs);

    {
        const u16x8* Wv = reinterpret_cast<const u16x8*>(Wt);
        #pragma unroll
        for (int i = 0; i < 8; ++i) {
            int idx = i * 256 + tid;
            int n = idx >> 4, s = idx & 15;
            int soff = (s * 16) ^ ((n & 7) << 4);
            *reinterpret_cast<u16x8*>(BsB + n * 256 + soff) = Wv[idx];
        }
    }
    {
        const u16x8* Av = reinterpret_cast<const u16x8*>(Ain);
        #pragma unroll
        for (int i = 0; i < 4; ++i) {
            int idx = i * 256 + tid;
            int r = idx >> 4, s = idx & 15;
            int row = base + r;
            u16x8 v;
            if (row < NN) v = Av[(size_t)row * 16 + s];
            else v = (u16x8){0,0,0,0,0,0,0,0};
            int soff = (s * 16) ^ ((r & 7) << 4);
            *reinterpret_cast<u16x8*>(AsB + r * 256 + soff) = v;
        }
    }
    __syncthreads();

    const int lane = tid & 63;
    const int w = tid >> 6;
    const int r = w * 16 + (lane & 15);
    const int kb = lane >> 4;
    const int n = lane & 15;

    bf16x8 a[4];
    #pragma unroll
    for (int kt = 0; kt < 4; ++kt) {
        int boff = (kt * 64 + kb * 16) ^ ((r & 7) << 4);
        a[kt] = *reinterpret_cast<bf16x8*>(AsB + r * 256 + boff);
    }

    f32x4 acc[8];
    #pragma unroll
    for (int ct = 0; ct < 8; ++ct) acc[ct] = (f32x4){0.f, 0.f, 0.f, 0.f};

    #pragma unroll
    for (int ct = 0; ct < 8; ++ct) {
        int col = ct * 16 + n;
        #pragma unroll
        for (int kt = 0; kt < 4; ++kt) {
            int boff = (kt * 64 + kb * 16) ^ ((col & 7) << 4);
            bf16x8 b = *reinterpret_cast<bf16x8*>(BsB + col * 256 + boff);
            acc[ct] = __builtin_amdgcn_mfma_f32_16x16x32_bf16(a[kt], b, acc[ct], 0, 0, 0);
        }
    }

    const int rbase = base + w * 16 + (lane >> 4) * 4;
    #pragma unroll
    for (int reg = 0; reg < 4; ++reg) {
        int node = rbase + reg;
        if (node < NN) {
            #pragma unroll
            for (int ct = 0; ct < 8; ++ct)
                Y[(size_t)node * FD + ct * 16 + n] = f2bf(acc[ct][reg]);
        }
    }
}

// ===== gather: H[v] = relu(Y[v] + mean_{u->v} Y[u] + bias); 16 thr/node =====
// Padded buckets (dummy idx NN -> zero row): 16-chunk = 1 coalesced eidx load
// + 16 shfl-broadcast independent row loads. POOL: per-graph sums via LDS.
template <bool POOL>
__global__ __launch_bounds__(256) void k_agg(
    const unsigned short* __restrict__ Y, const int* __restrict__ off,
    const int* __restrict__ degi, const int* __restrict__ eidx,
    const float* __restrict__ bias, unsigned short* __restrict__ H,
    const int* __restrict__ gid, float* __restrict__ hg_sum)
{
    __shared__ float hl[FD];
    int gid0 = 0;
    if (POOL) {
        if (threadIdx.x < FD) hl[threadIdx.x] = 0.0f;
        gid0 = gid[blockIdx.x * 16];
        __syncthreads();
    }
    const int t = blockIdx.x * 256 + threadIdx.x;
    const int v = t >> 4;                 // node
    const int l = t & 15;                 // 8-feature slice
    const int gb = threadIdx.x & 48;      // 16-lane group base within wave
    const int e0 = off[v];
    const int d  = degi[v];
    const int pd = (d + 15) & ~15;

    float a[8];
    #pragma unroll
    for (int j = 0; j < 8; ++j) a[j] = 0.0f;

    const u16x8* Yv = reinterpret_cast<const u16x8*>(Y);
    const int eend = e0 + pd;
    for (int e = e0; e < eend; e += 16) {
        int myidx = eidx[e + l];
        #pragma unroll
        for (int j = 0; j < 16; ++j) {
            int s = __shfl(myidx, gb + j, 64);
            u16x8 p = Yv[(size_t)s * 16 + l];
            #pragma unroll
            for (int jj = 0; jj < 8; ++jj) a[jj] += bf2f(p[jj]);
        }
    }

    const float inv = 1.0f / fmaxf((float)d, 1.0f);
    u16x8 sv = Yv[(size_t)v * 16 + l];
    const float4* bp = reinterpret_cast<const float4*>(bias + l * 8);
    float4 b0 = bp[0], b1 = bp[1];
    const float* bb[8] = { &b0.x, &b0.y, &b0.z, &b0.w, &b1.x, &b1.y, &b1.z, &b1.w };

    float hv[8];
    #pragma unroll
    for (int j = 0; j < 8; ++j)
        hv[j] = fmaxf(bf2f(sv[j]) + a[j] * inv + *bb[j], 0.0f);

    if (!POOL) {
        u16x8 o;
        #pragma unroll
        for (int j = 0; j < 8; ++j) o[j] = f2bf(hv[j]);
        reinterpret_cast<u16x8*>(H)[(size_t)v * 16 + l] = o;
    } else {
        int g = gid[v];
        int fo = l * 8;
        if (g == gid0) {
            #pragma unroll
            for (int j = 0; j < 8; ++j) atomicAdd(&hl[fo + j], hv[j]);
        } else {
            #pragma unroll
            for (int j = 0; j < 8; ++j) atomAddF(&hg_sum[(size_t)g * FD + fo + j], hv[j]);
        }
        __syncthreads();
        if (threadIdx.x < FD)
            atomAddF(&hg_sum[(size_t)gid0 * FD + threadIdx.x], hl[threadIdx.x]);
    }
}

// ===== fused decoder: one block per graph =====
__global__ __launch_bounds__(128) void k_dec(
    const float* __restrict__ hg_sum, const float* __restrict__ gcount,
    const float* __restrict__ Wd1, const float* __restrict__ bd1,
    const float* __restrict__ Wd2, const float* __restrict__ bd2,
    float* __restrict__ out)
{
    __shared__ float hgL[FD];
    __shared__ float t1L[FD];
    const int g = blockIdx.x;
    const int t = threadIdx.x;
    const float invc = 1.0f / fmaxf(gcount[g], 1.0f);

    float v = hg_sum[(size_t)g * FD + t] * invc;
    hgL[t] = v;
    out[(size_t)g * FD + t] = v;
    __syncthreads();

    float acc = bd1[t];
    #pragma unroll 8
    for (int k = 0; k < FD; ++k)
        acc += hgL[k] * Wd1[k * FD + t];
    t1L[t] = fmaxf(acc, 0.0f);
    __syncthreads();

    if (t < OUTD) {
        float acc2 = bd2[t];
        #pragma unroll 8
        for (int k = 0; k < FD; ++k)
            acc2 += t1L[k] * Wd2[k * OUTD + t];
        out[NG * FD + (size_t)g * OUTD + t] = acc2;
    }
}

extern "C" void kernel_launch(void* const* d_in, const int* in_sizes, int n_in,
                              void* d_out, int out_size, void* d_ws, size_t ws_size,
                              hipStream_t stream) {
    const float* feat = (const float*)d_in[0];
    const int*   src  = (const int*)d_in[1];
    const int*   dst  = (const int*)d_in[2];
    const int*   gid  = (const int*)d_in[3];
    const float* W1   = (const float*)d_in[4];
    const float* b1   = (const float*)d_in[5];
    const float* W2   = (const float*)d_in[6];
    const float* b2   = (const float*)d_in[7];
    const float* Wd1  = (const float*)d_in[8];
    const float* bd1  = (const float*)d_in[9];
    const float* Wd2  = (const float*)d_in[10];
    const float* bd2  = (const float*)d_in[11];
    float* out = (float*)d_out;

    // workspace layout (4-byte-word offsets; 16B-aligned where vector-accessed)
    char* wsb = (char*)d_ws;
    int*   degi   = (int*)wsb;                              // [100000]
    float* gcount = (float*)(wsb + 100000ll * 4);           // [64]
    float* hg_sum = (float*)(wsb + 100064ll * 4);           // [8192]
    int*   cnt    = (int*)(wsb + 108256ll * 4);             // [1] (pad to 108260)
    int*   off    = (int*)(wsb + 108260ll * 4);             // [100000]
    int*   cursor = (int*)(wsb + 208260ll * 4);             // [100000]
    int*   eidx   = (int*)(wsb + 308260ll * 4);             // [3200000] padded CSR
    unsigned short* W1t = (unsigned short*)(wsb + 3508260ll * 4);  // bf16 [16384]
    unsigned short* W2t = (unsigned short*)(wsb + 3516452ll * 4);  // bf16 [16384]
    unsigned short* Yb  = (unsigned short*)(wsb + 3524644ll * 4);  // bf16 [(NN+1)*128]
    unsigned short* H1  = (unsigned short*)(wsb + 9924708ll * 4);  // bf16 [NN*128]

    // zero degi + gcount + hg_sum + cnt
    hipMemsetAsync(d_ws, 0, (size_t)108260 * 4, stream);

    // prep: degree hist + graph counts || Wt convert + dummy-row zero
    k_prep<<<6250 + 129, 256, 0, stream>>>(dst, gid, degi, gcount,
                                           W1, W2, W1t, W2t, Yb + (size_t)NN * FD);
    // CSR offsets (padded buckets)
    k_off<<<(NN + 255) / 256, 256, 0, stream>>>(degi, cnt, off, cursor, eidx);
    // fill || gemm1 (y1 = feat @ W1), interleaved 4:1
    k_work<<<7815, 256, 0, stream>>>(src, dst, cursor, eidx, feat, W1t, Yb);
    // h1 = relu(y1 + mean-agg(y1) + b1)
    k_agg<false><<<NN * 16 / 256, 256, 0, stream>>>(Yb, off, degi, eidx, b1, H1, nullptr, nullptr);
    // y2 = h1 @ W2
    k_gemm2<<<(NN + 63) / 64, 256, 0, stream>>>(H1, W2t, Yb);
    // h2 pooled per graph
    k_agg<true><<<NN * 16 / 256, 256, 0, stream>>>(Yb, off, degi, eidx, b2, nullptr, gid, hg_sum);
    // pool divide + decoder
    k_dec<<<NG, 128, 0, stream>>>(hg_sum, gcount, Wd1, bd1, Wd2, bd2, out);
}

// Round 8
// 362.263 us; speedup vs baseline: 1.3225x; 1.1285x over previous
//
#include <hip/hip_runtime.h>

#define NN 100000
#define NE 1600000
#define FD 128
#define NG 64
#define OUTD 64

typedef __attribute__((ext_vector_type(8))) short bf16x8;
typedef __attribute__((ext_vector_type(4))) float f32x4;
typedef __attribute__((ext_vector_type(2))) float f32x2;
typedef __attribute__((ext_vector_type(8))) unsigned short u16x8;

static __device__ __forceinline__ void atomAddF(float* p, float v) {
    __hip_atomic_fetch_add(p, v, __ATOMIC_RELAXED, __HIP_MEMORY_SCOPE_AGENT);
}
static __device__ __forceinline__ int atomAddI(int* p, int v) {
    return __hip_atomic_fetch_add(p, v, __ATOMIC_RELAXED, __HIP_MEMORY_SCOPE_AGENT);
}
// fp32 -> bf16 round-to-nearest-even
static __device__ __forceinline__ unsigned short f2bf(float f) {
    unsigned int u = __float_as_uint(f);
    u += 0x7FFFu + ((u >> 16) & 1u);
    return (unsigned short)(u >> 16);
}
static __device__ __forceinline__ float bf2f(unsigned short h) {
    return __uint_as_float(((unsigned int)h) << 16);
}
// fp32 -> fp8 e4m3 (OCP on gfx950), HW convert
static __device__ __forceinline__ unsigned char f2fp8(float v) {
    return (unsigned char)(__builtin_amdgcn_cvt_pk_fp8_f32(v, v, 0, false) & 0xff);
}

// ===== k_prep: [0..6249] degree hist + graph counts; [6250..] Wt + dummy rows =====
__global__ __launch_bounds__(256) void k_prep(
    const int* __restrict__ dst, const int* __restrict__ gid,
    int* __restrict__ degi, float* __restrict__ gcount,
    const float* __restrict__ W1, const float* __restrict__ W2,
    unsigned short* __restrict__ W1t, unsigned short* __restrict__ W2t,
    unsigned short* __restrict__ Ydummy, unsigned int* __restrict__ Y8dummy)
{
    if (blockIdx.x < 6250) {
        __shared__ float c[NG];
        if (threadIdx.x < NG) c[threadIdx.x] = 0.0f;
        __syncthreads();
        int i = blockIdx.x * 256 + threadIdx.x;
        if (i < NE) atomAddI(&degi[dst[i]], 1);
        if (i < NN) atomicAdd(&c[gid[i]], 1.0f);
        __syncthreads();
        if (threadIdx.x < NG) {
            float v = c[threadIdx.x];
            if (v != 0.0f) atomAddF(&gcount[threadIdx.x], v);
        }
    } else {
        int idx = (blockIdx.x - 6250) * 256 + threadIdx.x;
        if (idx < 32768) {
            const float* W = (idx < 16384) ? W1 : W2;
            unsigned short* Wt = (idx < 16384) ? W1t : W2t;
            int i = idx & 16383;
            int k = i >> 7, n = i & 127;
            Wt[n * 128 + k] = f2bf(W[i]);
        } else if (idx < 32768 + FD) {
            Ydummy[idx - 32768] = 0;          // zero bf16 Y row NN
        } else if (idx < 32768 + FD + 32) {
            Y8dummy[idx - 32768 - FD] = 0;    // zero fp8 Y row NN (32 uints)
        }
    }
}

// ===== CSR range claim, buckets padded to multiples of 16 =====
__global__ void k_off(const int* __restrict__ degi, int* __restrict__ cnt,
                      int* __restrict__ off, int* __restrict__ cursor,
                      int* __restrict__ eidx) {
    int i = blockIdx.x * 256 + threadIdx.x;
    int lane = threadIdx.x & 63;
    int d = (i < NN) ? degi[i] : 0;
    int rd = (d + 15) & ~15;
    int incl = rd;
    #pragma unroll
    for (int s = 1; s < 64; s <<= 1) {
        int n = __shfl_up(incl, s, 64);
        if (lane >= s) incl += n;
    }
    int base = 0;
    if (lane == 63) base = atomAddI(cnt, incl);
    base = __shfl(base, 63, 64);
    if (i < NN) {
        int o = base + incl - rd;
        off[i] = o;
        cursor[i] = o;
        for (int j = d; j < rd; ++j) eidx[o + j] = NN;
    }
}

// ===== no-LDS MFMA gemm body: Y (bf16+fp8) = A @ W, A fp32 from global =====
static __device__ __forceinline__ void gemm_body(
    int base, const float* __restrict__ feat, const unsigned short* __restrict__ Wt,
    unsigned short* __restrict__ Y, unsigned char* __restrict__ Y8)
{
    const int lane = threadIdx.x & 63;
    const int w = threadIdx.x >> 6;
    const int r = lane & 15;
    const int kb = lane >> 4;
    const int row = base + w * 16 + r;
    const bool rok = row < NN;

    bf16x8 a[4];
    #pragma unroll
    for (int kt = 0; kt < 4; ++kt) {
        float4 lo = {0,0,0,0}, hi = {0,0,0,0};
        if (rok) {
            const float4* p = reinterpret_cast<const float4*>(
                feat + (size_t)row * FD + kt * 32 + kb * 8);
            lo = p[0]; hi = p[1];
        }
        bf16x8 t;
        t[0] = (short)f2bf(lo.x); t[1] = (short)f2bf(lo.y);
        t[2] = (short)f2bf(lo.z); t[3] = (short)f2bf(lo.w);
        t[4] = (short)f2bf(hi.x); t[5] = (short)f2bf(hi.y);
        t[6] = (short)f2bf(hi.z); t[7] = (short)f2bf(hi.w);
        a[kt] = t;
    }

    f32x4 acc[8];
    #pragma unroll
    for (int ct = 0; ct < 8; ++ct) acc[ct] = (f32x4){0.f, 0.f, 0.f, 0.f};

    const int n = lane & 15;
    #pragma unroll
    for (int ct = 0; ct < 8; ++ct) {
        int col = ct * 16 + n;
        #pragma unroll
        for (int kt = 0; kt < 4; ++kt) {
            bf16x8 b = *reinterpret_cast<const bf16x8*>(
                Wt + (size_t)col * FD + kt * 32 + kb * 8);
            acc[ct] = __builtin_amdgcn_mfma_f32_16x16x32_bf16(a[kt], b, acc[ct], 0, 0, 0);
        }
    }

    const int rbase = base + w * 16 + (lane >> 4) * 4;
    #pragma unroll
    for (int reg = 0; reg < 4; ++reg) {
        int node = rbase + reg;
        if (node < NN) {
            #pragma unroll
            for (int ct = 0; ct < 8; ++ct) {
                float v = acc[ct][reg];
                Y[(size_t)node * FD + ct * 16 + n] = f2bf(v);
                Y8[(size_t)node * FD + ct * 16 + n] = f2fp8(v);
            }
        }
    }
}

// ===== k_work: [g%5==0] gemm1 (no LDS); else CSR fill =====
__global__ __launch_bounds__(256) void k_work(
    const int* __restrict__ src, const int* __restrict__ dst,
    int* __restrict__ cursor, int* __restrict__ eidx,
    const float* __restrict__ feat, const unsigned short* __restrict__ Wt,
    unsigned short* __restrict__ Y, unsigned char* __restrict__ Y8)
{
    int g = blockIdx.x;
    if (g % 5 == 0) {
        gemm_body((g / 5) * 64, feat, Wt, Y, Y8);
    } else {
        int fb = g - g / 5 - 1;
        int e = fb * 256 + threadIdx.x;
        if (e < NE) {
            int v = dst[e];
            int p = atomAddI(&cursor[v], 1);
            eidx[p] = src[e];
        }
    }
}

// ===== LDS MFMA GEMM for layer 2 (A bf16): Y (bf16+fp8) = A @ W =====
__global__ __launch_bounds__(256) void k_gemm2(
    const unsigned short* __restrict__ Ain, const unsigned short* __restrict__ Wt,
    unsigned short* __restrict__ Y, unsigned char* __restrict__ Y8)
{
    __shared__ unsigned short As[64 * 128];    // 16 KB
    __shared__ unsigned short Bs[128 * 128];   // 32 KB
    const int tid = threadIdx.x;
    const int base = blockIdx.x * 64;
    char* AsB = reinterpret_cast<char*>(As);
    char* BsB = reinterpret_cast<char*>(Bs);

    {
        const u16x8* Wv = reinterpret_cast<const u16x8*>(Wt);
        #pragma unroll
        for (int i = 0; i < 8; ++i) {
            int idx = i * 256 + tid;
            int n = idx >> 4, s = idx & 15;
            int soff = (s * 16) ^ ((n & 7) << 4);
            *reinterpret_cast<u16x8*>(BsB + n * 256 + soff) = Wv[idx];
        }
    }
    {
        const u16x8* Av = reinterpret_cast<const u16x8*>(Ain);
        #pragma unroll
        for (int i = 0; i < 4; ++i) {
            int idx = i * 256 + tid;
            int r = idx >> 4, s = idx & 15;
            int row = base + r;
            u16x8 v;
            if (row < NN) v = Av[(size_t)row * 16 + s];
            else v = (u16x8){0,0,0,0,0,0,0,0};
            int soff = (s * 16) ^ ((r & 7) << 4);
            *reinterpret_cast<u16x8*>(AsB + r * 256 + soff) = v;
        }
    }
    __syncthreads();

    const int lane = tid & 63;
    const int w = tid >> 6;
    const int r = w * 16 + (lane & 15);
    const int kb = lane >> 4;
    const int n = lane & 15;

    bf16x8 a[4];
    #pragma unroll
    for (int kt = 0; kt < 4; ++kt) {
        int boff = (kt * 64 + kb * 16) ^ ((r & 7) << 4);
        a[kt] = *reinterpret_cast<bf16x8*>(AsB + r * 256 + boff);
    }

    f32x4 acc[8];
    #pragma unroll
    for (int ct = 0; ct < 8; ++ct) acc[ct] = (f32x4){0.f, 0.f, 0.f, 0.f};

    #pragma unroll
    for (int ct = 0; ct < 8; ++ct) {
        int col = ct * 16 + n;
        #pragma unroll
        for (int kt = 0; kt < 4; ++kt) {
            int boff = (kt * 64 + kb * 16) ^ ((col & 7) << 4);
            bf16x8 b = *reinterpret_cast<bf16x8*>(BsB + col * 256 + boff);
            acc[ct] = __builtin_amdgcn_mfma_f32_16x16x32_bf16(a[kt], b, acc[ct], 0, 0, 0);
        }
    }

    const int rbase = base + w * 16 + (lane >> 4) * 4;
    #pragma unroll
    for (int reg = 0; reg < 4; ++reg) {
        int node = rbase + reg;
        if (node < NN) {
            #pragma unroll
            for (int ct = 0; ct < 8; ++ct) {
                float v = acc[ct][reg];
                Y[(size_t)node * FD + ct * 16 + n] = f2bf(v);
                Y8[(size_t)node * FD + ct * 16 + n] = f2fp8(v);
            }
        }
    }
}

// ===== gather: H[v] = relu(Y[v] + mean_{u->v} Y8[u] + bias) =====
// Neighbors from the fp8 table (12.9 MB working set, 8 B/thread/edge);
// self-term from bf16 Y (exact, coalesced). 16-chunk shfl-broadcast loads.
template <bool POOL>
__global__ __launch_bounds__(256) void k_agg(
    const unsigned short* __restrict__ Y, const unsigned char* __restrict__ Y8,
    const int* __restrict__ off, const int* __restrict__ degi,
    const int* __restrict__ eidx, const float* __restrict__ bias,
    unsigned short* __restrict__ H,
    const int* __restrict__ gid, float* __restrict__ hg_sum)
{
    __shared__ float hl[FD];
    int gid0 = 0;
    if (POOL) {
        if (threadIdx.x < FD) hl[threadIdx.x] = 0.0f;
        gid0 = gid[blockIdx.x * 16];
        __syncthreads();
    }
    const int t = blockIdx.x * 256 + threadIdx.x;
    const int v = t >> 4;                 // node
    const int l = t & 15;                 // 8-feature slice
    const int gb = threadIdx.x & 48;      // 16-lane group base within wave
    const int e0 = off[v];
    const int d  = degi[v];
    const int pd = (d + 15) & ~15;

    float a[8];
    #pragma unroll
    for (int j = 0; j < 8; ++j) a[j] = 0.0f;

    const uint2* Y8v = reinterpret_cast<const uint2*>(Y8);
    const int eend = e0 + pd;
    for (int e = e0; e < eend; e += 16) {
        int myidx = eidx[e + l];
        #pragma unroll
        for (int j = 0; j < 16; ++j) {
            int s = __shfl(myidx, gb + j, 64);
            uint2 q = Y8v[(size_t)s * 16 + l];
            f32x2 v0 = __builtin_amdgcn_cvt_pk_f32_fp8((int)q.x, false);
            f32x2 v1 = __builtin_amdgcn_cvt_pk_f32_fp8((int)q.x, true);
            f32x2 v2 = __builtin_amdgcn_cvt_pk_f32_fp8((int)q.y, false);
            f32x2 v3 = __builtin_amdgcn_cvt_pk_f32_fp8((int)q.y, true);
            a[0] += v0[0]; a[1] += v0[1]; a[2] += v1[0]; a[3] += v1[1];
            a[4] += v2[0]; a[5] += v2[1]; a[6] += v3[0]; a[7] += v3[1];
        }
    }

    const float inv = 1.0f / fmaxf((float)d, 1.0f);
    const u16x8* Yv = reinterpret_cast<const u16x8*>(Y);
    u16x8 sv = Yv[(size_t)v * 16 + l];
    const float4* bp = reinterpret_cast<const float4*>(bias + l * 8);
    float4 b0 = bp[0], b1 = bp[1];
    const float* bb[8] = { &b0.x, &b0.y, &b0.z, &b0.w, &b1.x, &b1.y, &b1.z, &b1.w };

    float hv[8];
    #pragma unroll
    for (int j = 0; j < 8; ++j)
        hv[j] = fmaxf(bf2f(sv[j]) + a[j] * inv + *bb[j], 0.0f);

    if (!POOL) {
        u16x8 o;
        #pragma unroll
        for (int j = 0; j < 8; ++j) o[j] = f2bf(hv[j]);
        reinterpret_cast<u16x8*>(H)[(size_t)v * 16 + l] = o;
    } else {
        int g = gid[v];
        int fo = l * 8;
        if (g == gid0) {
            #pragma unroll
            for (int j = 0; j < 8; ++j) atomicAdd(&hl[fo + j], hv[j]);
        } else {
            #pragma unroll
            for (int j = 0; j < 8; ++j) atomAddF(&hg_sum[(size_t)g * FD + fo + j], hv[j]);
        }
        __syncthreads();
        if (threadIdx.x < FD)
            atomAddF(&hg_sum[(size_t)gid0 * FD + threadIdx.x], hl[threadIdx.x]);
    }
}

// ===== fused decoder: one block per graph =====
__global__ __launch_bounds__(128) void k_dec(
    const float* __restrict__ hg_sum, const float* __restrict__ gcount,
    const float* __restrict__ Wd1, const float* __restrict__ bd1,
    const float* __restrict__ Wd2, const float* __restrict__ bd2,
    float* __restrict__ out)
{
    __shared__ float hgL[FD];
    __shared__ float t1L[FD];
    const int g = blockIdx.x;
    const int t = threadIdx.x;
    const float invc = 1.0f / fmaxf(gcount[g], 1.0f);

    float v = hg_sum[(size_t)g * FD + t] * invc;
    hgL[t] = v;
    out[(size_t)g * FD + t] = v;
    __syncthreads();

    float acc = bd1[t];
    #pragma unroll 8
    for (int k = 0; k < FD; ++k)
        acc += hgL[k] * Wd1[k * FD + t];
    t1L[t] = fmaxf(acc, 0.0f);
    __syncthreads();

    if (t < OUTD) {
        float acc2 = bd2[t];
        #pragma unroll 8
        for (int k = 0; k < FD; ++k)
            acc2 += t1L[k] * Wd2[k * OUTD + t];
        out[NG * FD + (size_t)g * OUTD + t] = acc2;
    }
}

extern "C" void kernel_launch(void* const* d_in, const int* in_sizes, int n_in,
                              void* d_out, int out_size, void* d_ws, size_t ws_size,
                              hipStream_t stream) {
    const float* feat = (const float*)d_in[0];
    const int*   src  = (const int*)d_in[1];
    const int*   dst  = (const int*)d_in[2];
    const int*   gid  = (const int*)d_in[3];
    const float* W1   = (const float*)d_in[4];
    const float* b1   = (const float*)d_in[5];
    const float* W2   = (const float*)d_in[6];
    const float* b2   = (const float*)d_in[7];
    const float* Wd1  = (const float*)d_in[8];
    const float* bd1  = (const float*)d_in[9];
    const float* Wd2  = (const float*)d_in[10];
    const float* bd2  = (const float*)d_in[11];
    float* out = (float*)d_out;

    // workspace layout (4-byte-word offsets; 8/16B-aligned where vector-accessed)
    char* wsb = (char*)d_ws;
    int*   degi   = (int*)wsb;                              // [100000]
    float* gcount = (float*)(wsb + 100000ll * 4);           // [64]
    float* hg_sum = (float*)(wsb + 100064ll * 4);           // [8192]
    int*   cnt    = (int*)(wsb + 108256ll * 4);             // [1] (pad to 108260)
    int*   off    = (int*)(wsb + 108260ll * 4);             // [100000]
    int*   cursor = (int*)(wsb + 208260ll * 4);             // [100000]
    int*   eidx   = (int*)(wsb + 308260ll * 4);             // [3200000] padded CSR
    unsigned short* W1t = (unsigned short*)(wsb + 3508260ll * 4);  // bf16 [16384]
    unsigned short* W2t = (unsigned short*)(wsb + 3516452ll * 4);  // bf16 [16384]
    unsigned short* Yb  = (unsigned short*)(wsb + 3524644ll * 4);  // bf16 [(NN+1)*128]
    unsigned short* H1  = (unsigned short*)(wsb + 9931108ll * 4);  // bf16 [NN*128]
    unsigned char*  Y8  = (unsigned char*)(wsb + 16331108ll * 4);  // fp8 [(NN+1)*128]

    // zero degi + gcount + hg_sum + cnt
    hipMemsetAsync(d_ws, 0, (size_t)108260 * 4, stream);

    // prep: degree hist + graph counts || Wt convert + dummy-row zeroes
    k_prep<<<6250 + 130, 256, 0, stream>>>(dst, gid, degi, gcount, W1, W2, W1t, W2t,
                                           Yb + (size_t)NN * FD,
                                           (unsigned int*)(Y8 + (size_t)NN * FD));
    // CSR offsets (padded buckets)
    k_off<<<(NN + 255) / 256, 256, 0, stream>>>(degi, cnt, off, cursor, eidx);
    // fill || gemm1 (y1 = feat @ W1), interleaved 4:1
    k_work<<<7815, 256, 0, stream>>>(src, dst, cursor, eidx, feat, W1t, Yb, Y8);
    // h1 = relu(y1_self + mean-agg(y1_fp8) + b1)
    k_agg<false><<<NN * 16 / 256, 256, 0, stream>>>(Yb, Y8, off, degi, eidx, b1, H1, nullptr, nullptr);
    // y2 = h1 @ W2
    k_gemm2<<<(NN + 63) / 64, 256, 0, stream>>>(H1, W2t, Yb, Y8);
    // h2 pooled per graph
    k_agg<true><<<NN * 16 / 256, 256, 0, stream>>>(Yb, Y8, off, degi, eidx, b2, nullptr, gid, hg_sum);
    // pool divide + decoder
    k_dec<<<NG, 128, 0, stream>>>(hg_sum, gcount, Wd1, bd1, Wd2, bd2, out);
}